// Round 11
// baseline (404.277 us; speedup 1.0000x reference)
//
#include <hip/hip_runtime.h>
#include <math.h>

#define F_IN 128
#define HID  64
#define NCLS 40
#define PART_CHUNK 4096   // 782 partition blocks (parallelism)
#define CAP 4608          // total per-bucket capacity: mean 4096, sigma 64 -> 8 sigma headroom
#define CAPX 768          // per-(bucket,XCD) capacity: mean 512, sigma ~23 -> 11 sigma headroom
#define MAXNB 1024
#define ASTRIDE 132       // f16 row stride (128 + 4 pad)
#define GSTRIDE 72        // f16 row stride (64 + 8 pad) for fused gemm2 tiles

typedef _Float16 half8 __attribute__((ext_vector_type(8)));
typedef _Float16 half2t __attribute__((ext_vector_type(2)));
typedef float floatx4 __attribute__((ext_vector_type(4)));

// load 8 f16 from an 8B-aligned (not necessarily 16B) pointer (LDS staging use)
__device__ inline half8 ld_half8_u8(const _Float16* p) {
    union { uint2 u[2]; half8 h; } r;
    r.u[0] = *(const uint2*)p;
    r.u[1] = *(const uint2*)(p + 4);
    return r.h;
}

// ---------------- fused: [0,nPart) edge partition | [nPart, nPart+nGemm) gemm1 ----------------
// partition: DIRECT per-edge device atomics on (bucket,XCD) counters — no LDS histogram, no
// barriers, no per-bucket reservation loop. XCD segregation (blockIdx&7) still guarantees all
// writers of a 64B pkBuf line share one private L2, so partial writes merge before eviction.
// 16 independent atomic->store chains per thread pipeline the LLC atomic latency.
// gemm1: h1 = f16(x @ W1) via 16x16x32 f16 MFMA, 64 nodes/block (LDS-staged A and W1^T).
__global__ __launch_bounds__(256) void fused_part_gemm1(const int* __restrict__ src,
                                                        const int* __restrict__ dst,
                                                        int* __restrict__ bCur,
                                                        int* __restrict__ pkBuf,
                                                        int E, int NB, int nPart,
                                                        const float* __restrict__ x,
                                                        const float* __restrict__ W1,
                                                        _Float16* __restrict__ h1, int n) {
    __shared__ __align__(16) char smem[2 * 64 * ASTRIDE * 2];   // 33792 B arena (gemm1 only)
    int tid = threadIdx.x;
    if ((int)blockIdx.x < nPart) {
        // ---- partition path: pure streaming + direct atomics ----
        int xcd = (int)blockIdx.x & 7;     // XCD heuristic (round-robin dispatch); perf-only
        int e0 = blockIdx.x * PART_CHUNK;
        int s_[16], d_[16];
#pragma unroll
        for (int i = 0; i < 16; ++i) {
            int e = e0 + i * 256 + tid;
            if (e < E) { s_[i] = src[e]; d_[i] = dst[e]; }
        }
#pragma unroll
        for (int i = 0; i < 16; ++i) {
            int e = e0 + i * 256 + tid;
            if (e < E) {
                int b = d_[i] >> 7;
                int pos = atomicAdd(&bCur[b * 8 + xcd], 1);
                pkBuf[(size_t)(b * 8 + xcd) * CAPX + pos] = (s_[i] << 7) | (d_[i] & 127);
            }
        }
    } else {
        // ---- gemm1 path ----
        _Float16* Ah = (_Float16*)smem;            // 64*ASTRIDE
        _Float16* Wt = Ah + 64 * ASTRIDE;          // 64*ASTRIDE
        int node0 = ((int)blockIdx.x - nPart) * 64;
#pragma unroll
        for (int i = 0; i < 8; ++i) {              // 8*256*4 = 8192 floats = 64x128
            int f = (i * 256 + tid) * 4;
            int m = f >> 7, k = f & 127;
            float4 v = (node0 + m < n) ? ((const float4*)(x + (size_t)(node0 + m) * F_IN))[k >> 2]
                                       : make_float4(0.f, 0.f, 0.f, 0.f);
            _Float16* p = &Ah[m * ASTRIDE + k];
            p[0] = (_Float16)v.x; p[1] = (_Float16)v.y; p[2] = (_Float16)v.z; p[3] = (_Float16)v.w;
        }
#pragma unroll
        for (int i = 0; i < 32; ++i) {
            int f = i * 256 + tid;                 // f = k*64 + nout
            int k = f >> 6, nn = f & 63;
            Wt[nn * ASTRIDE + k] = (_Float16)W1[f];
        }
        __syncthreads();
        int wave = tid >> 6, lane = tid & 63;
        int m0 = wave * 16;
        int col = lane & 15, quad = lane >> 4;
        floatx4 acc[4] = {{0,0,0,0},{0,0,0,0},{0,0,0,0},{0,0,0,0}};
#pragma unroll
        for (int kk = 0; kk < 4; ++kk) {
            int kbase = kk * 32 + quad * 8;
            half8 a = ld_half8_u8(&Ah[(m0 + col) * ASTRIDE + kbase]);
#pragma unroll
            for (int t = 0; t < 4; ++t) {
                half8 b = ld_half8_u8(&Wt[(t * 16 + col) * ASTRIDE + kbase]);
                acc[t] = __builtin_amdgcn_mfma_f32_16x16x32_f16(a, b, acc[t], 0, 0, 0);
            }
        }
#pragma unroll
        for (int t = 0; t < 4; ++t)
#pragma unroll
            for (int r = 0; r < 4; ++r) {
                int node = node0 + m0 + quad * 4 + r;
                if (node < n) h1[(size_t)node * HID + t * 16 + col] = (_Float16)acc[t][r];
            }
    }
}

// ---------------- per-bucket: gather 8 XCD segments -> LDS, counts -> ptr/pEnd + dinv,
//                  permute in LDS, stream sIdx to the bucket's FIXED sparse region (b*CAP),
//                  AND pre-scale h1 rows by dinv. No global scan needed (sparse layout).
__global__ __launch_bounds__(256) void bucket_finalize(const int* __restrict__ bCur,
                                                       const int* __restrict__ pkBuf,
                                                       int* __restrict__ ptr,
                                                       int* __restrict__ pEnd,
                                                       float* __restrict__ dinv,
                                                       int* __restrict__ sIdx,
                                                       _Float16* __restrict__ h1,
                                                       int n, int E) {
    __shared__ int cnt128[128];
    __shared__ int sc[128];
    __shared__ int cur[128];
    __shared__ float sdinv[128];
    __shared__ int segoff[9];
    __shared__ int ebuf[CAP];    // staged packed edges (18432 B)
    __shared__ int stage[CAP];   // permuted src indices (18432 B)
    int b = blockIdx.x;
    int node0 = b << 7;
    int tid = threadIdx.x;
    if (tid < 128) cnt128[tid] = 0;
    if (tid == 0) {
        int o = 0;
#pragma unroll
        for (int x = 0; x < 8; ++x) { segoff[x] = o; o += bCur[b * 8 + x]; }
        segoff[8] = o;
    }
    __syncthreads();
    int cnt = segoff[8];
    int dbase = b * CAP;               // fixed sparse region base (no scan)
    for (int x = 0; x < 8; ++x) {
        int off = segoff[x], len = segoff[x + 1] - off;
        const int* s = pkBuf + (size_t)(b * 8 + x) * CAPX;
        for (int j = tid; j < len; j += 256) {
            int p = s[j];
            ebuf[off + j] = p;
            atomicAdd(&cnt128[p & 127], 1);
        }
    }
    __syncthreads();
    // ---- 128-entry inclusive scan via 2-wave shfl (1 barrier instead of 14) ----
    int v = 0;
    if (tid < 128) {
        v = cnt128[tid];
        int vv = v;
        int lane = tid & 63;
#pragma unroll
        for (int off = 1; off < 64; off <<= 1) {
            int t = __shfl_up(vv, off, 64);
            if (lane >= off) vv += t;
        }
        sc[tid] = vv;
    }
    __syncthreads();
    if (tid >= 64 && tid < 128) sc[tid] += sc[63];
    __syncthreads();
    if (tid < 128) {
        cur[tid] = sc[tid] - v;            // LOCAL exclusive offset within bucket
        float dv = rsqrtf((float)v + 1.0f);   // +1 self loop
        sdinv[tid] = dv;
        int node = node0 + tid;
        if (node < n) {
            int p0 = dbase + sc[tid] - v;
            ptr[node] = p0;
            pEnd[node] = p0 + v;
            dinv[node] = dv;
        }
    }
    __syncthreads();
    for (int j = tid; j < cnt; j += 256) {
        int p = ebuf[j];
        int pos = atomicAdd(&cur[p & 127], 1);
        stage[pos] = p >> 7;
    }
    __syncthreads();
    for (int j = tid; j < cnt; j += 256)   // coalesced stream-out into the sparse region
        sIdx[dbase + j] = stage[j];
    // ---- in-place table pre-scale: h1[node] *= dinv[node] for this bucket's 128 nodes ----
#pragma unroll
    for (int pass = 0; pass < 4; ++pass) {
        int idx = pass * 256 + tid;
        int nd = node0 + (idx >> 3);
        if (nd < n) {
            float dv = sdinv[idx >> 3];
            half8* p = (half8*)(h1 + (size_t)nd * HID) + (idx & 7);
            half8 hv = *p;
#pragma unroll
            for (int j = 0; j < 8; ++j) hv[j] = (_Float16)((float)hv[j] * dv);
            *p = hv;
        }
    }
}

// ---------------- CSR gather: 4 nodes/wave, 16 lanes/node (2 slots x 8 chunks) ----
// 2-stage software pipeline (idx 2 iters ahead, rows 1 iter ahead).
// Table rows arrive PRE-SCALED by dinv[src]; loop is weight-free (validity masks only).
// RELU=true  (layer 1): stores h' = dinv[d] * relu(dinv[d]*sum + b1)  [pre-scaled for layer 2]
// RELU=false (layer 2, FUSED): g = dinv[d]*sum stays on-chip; block stages its 16 g-rows in
//   LDS and wave 0 computes out = log_softmax(g @ W2 + b2) directly.
template<bool RELU>
__global__ __launch_bounds__(256) void gather4(const int* __restrict__ ptr,
                                               const int* __restrict__ pEnd,
                                               const int* __restrict__ sIdx,
                                               const float* __restrict__ dinv,
                                               const _Float16* __restrict__ hin,
                                               const float* __restrict__ bias,
                                               _Float16* __restrict__ hout,
                                               const float* __restrict__ W2,
                                               const float* __restrict__ b2,
                                               float* __restrict__ out, int n) {
    __shared__ _Float16 gt[16 * GSTRIDE];   // 2304 B: 16 g-rows (fused path)
    __shared__ _Float16 wt[48 * GSTRIDE];   // 6912 B: W2^T zero-padded to 48 cols
    int tid = threadIdx.x, wave = tid >> 6, lane = tid & 63;
    int ng   = lane >> 4;         // node group 0..3
    int slot = (lane >> 3) & 1;   // edge slot 0..1
    int fq   = lane & 7;          // 16B chunk within 128B row
    int node = blockIdx.x * 16 + wave * 4 + ng;
    bool valid = node < n;
    int nodeC = valid ? node : 0;
    int beg = ptr[nodeC];
    int end = valid ? pEnd[nodeC] : beg;
    float di = dinv[nodeC];
    float a0[8] = {0,0,0,0,0,0,0,0}, a1[8] = {0,0,0,0,0,0,0,0};

    if (!RELU) {
        // stage W2^T (f32 -> f16) while the gather below hides the latency
#pragma unroll
        for (int i = 0; i < 12; ++i) {      // 3072 elems: f = c*64 + k
            int f = i * 256 + tid;
            int c = f >> 6, k = f & 63;
            wt[c * GSTRIDE + k] = (c < NCLS) ? (_Float16)W2[k * NCLS + c] : (_Float16)0.f;
        }
    }

    if (slot == 0 && valid) {     // self loop: table row already carries dinv[node]
        half8 v = *(const half8*)(hin + nodeC * HID + fq * 8);
#pragma unroll
        for (int j = 0; j < 8; ++j) a0[j] = (float)v[j];
    }
    const _Float16 ONE = (_Float16)1.0f, ZEROH = (_Float16)0.0f;
    if (beg < end) {
        // ---- pipeline preamble: idx(0), idx(1), rows(0) ----
        int ja0 = beg + slot, jb0 = ja0 + 2, jc0 = ja0 + 4, jd0 = ja0 + 6;
        bool va = ja0 < end, vb = jb0 < end, vc = jc0 < end, vd = jd0 < end;
        int sa0 = sIdx[va ? ja0 : beg];
        int sb0 = sIdx[vb ? jb0 : beg];
        int sc0 = sIdx[vc ? jc0 : beg];
        int sd0 = sIdx[vd ? jd0 : beg];
        int ja1 = ja0 + 8, jb1 = jb0 + 8, jc1 = jc0 + 8, jd1 = jd0 + 8;
        bool va1 = ja1 < end, vb1 = jb1 < end, vc1 = jc1 < end, vd1 = jd1 < end;
        int sa1 = sIdx[va1 ? ja1 : beg];
        int sb1 = sIdx[vb1 ? jb1 : beg];
        int sc1 = sIdx[vc1 ? jc1 : beg];
        int sd1 = sIdx[vd1 ? jd1 : beg];
        half8 ra = *(const half8*)(hin + (size_t)sa0 * HID + fq * 8);
        half8 rb = *(const half8*)(hin + (size_t)sb0 * HID + fq * 8);
        half8 rc = *(const half8*)(hin + (size_t)sc0 * HID + fq * 8);
        half8 rd = *(const half8*)(hin + (size_t)sd0 * HID + fq * 8);
        for (int j0 = beg; j0 < end; j0 += 8) {
            // issue rows(i+1) — indices already resolved last iteration
            half8 ra2 = *(const half8*)(hin + (size_t)sa1 * HID + fq * 8);
            half8 rb2 = *(const half8*)(hin + (size_t)sb1 * HID + fq * 8);
            half8 rc2 = *(const half8*)(hin + (size_t)sc1 * HID + fq * 8);
            half8 rd2 = *(const half8*)(hin + (size_t)sd1 * HID + fq * 8);
            // issue idx(i+2)
            int ja2 = j0 + 16 + slot, jb2 = ja2 + 2, jc2 = ja2 + 4, jd2 = ja2 + 6;
            bool va2 = ja2 < end, vb2 = jb2 < end, vc2 = jc2 < end, vd2 = jd2 < end;
            int sa2 = sIdx[va2 ? ja2 : beg];
            int sb2 = sIdx[vb2 ? jb2 : beg];
            int sc2 = sIdx[vc2 ? jc2 : beg];
            int sd2 = sIdx[vd2 ? jd2 : beg];
            // consume rows(i) — issued a full iteration ago
#if __has_builtin(__builtin_amdgcn_fdot2)
            half2t wab = { va ? ONE : ZEROH, vb ? ONE : ZEROH };
            half2t wcd = { vc ? ONE : ZEROH, vd ? ONE : ZEROH };
#pragma unroll
            for (int j = 0; j < 8; ++j) {
                half2t pab = { ra[j], rb[j] };
                half2t pcd = { rc[j], rd[j] };
                a0[j] = __builtin_amdgcn_fdot2(pab, wab, a0[j], false);
                a1[j] = __builtin_amdgcn_fdot2(pcd, wcd, a1[j], false);
            }
#else
            float wa = va ? 1.f : 0.f, wb = vb ? 1.f : 0.f, wc = vc ? 1.f : 0.f, wd = vd ? 1.f : 0.f;
#pragma unroll
            for (int j = 0; j < 8; ++j) {
                a0[j] = fmaf((float)ra[j], wa, a0[j]);
                a0[j] = fmaf((float)rb[j], wb, a0[j]);
                a1[j] = fmaf((float)rc[j], wc, a1[j]);
                a1[j] = fmaf((float)rd[j], wd, a1[j]);
            }
#endif
            // rotate pipeline state
            ra = ra2; rb = rb2; rc = rc2; rd = rd2;
            va = va1; vb = vb1; vc = vc1; vd = vd1;
            sa1 = sa2; sb1 = sb2; sc1 = sc2; sd1 = sd2;
            va1 = va2; vb1 = vb2; vc1 = vc2; vd1 = vd2;
        }
    }
#pragma unroll
    for (int j = 0; j < 8; ++j) {
        a0[j] += a1[j];
        a0[j] += __shfl_xor(a0[j], 8, 64);     // combine the 2 slots (1 round)
    }

    if (RELU) {
        // ---- layer-1 epilogue: store h' = dinv * relu(dinv*sum + b1) ----
        if (slot == 0 && valid) {
            union { half8 h; uint4 u; } o;
#pragma unroll
            for (int j = 0; j < 8; ++j) {
                float v = di * a0[j];
                v = fmaxf(v + bias[fq * 8 + j], 0.f) * di;   // pre-scale for next layer
                o.h[j] = (_Float16)v;
            }
            *(uint4*)(hout + nodeC * HID + fq * 8) = o.u;
        }
    } else {
        // ---- FUSED layer-2 epilogue: g-rows -> LDS, wave 0 does gemm2 + logsoftmax ----
        if (slot == 0) {
            int row = wave * 4 + ng;           // 0..15  (invalid nodes: a0 all zero)
#pragma unroll
            for (int j = 0; j < 8; ++j)
                gt[row * GSTRIDE + fq * 8 + j] = (_Float16)(di * a0[j]);
        }
        __syncthreads();
        if (wave == 0) {
            int col = lane & 15, quad = lane >> 4;
            floatx4 acc[3] = {{0,0,0,0},{0,0,0,0},{0,0,0,0}};
#pragma unroll
            for (int kk = 0; kk < 2; ++kk) {
                int kbase = kk * 32 + quad * 8;
                half8 a = *(const half8*)&gt[col * GSTRIDE + kbase];   // A[m=col][k]
#pragma unroll
                for (int t = 0; t < 3; ++t) {
                    half8 b = *(const half8*)&wt[(t * 16 + col) * GSTRIDE + kbase];
                    acc[t] = __builtin_amdgcn_mfma_f32_16x16x32_f16(a, b, acc[t], 0, 0, 0);
                }
            }
            float bb[3];
#pragma unroll
            for (int t = 0; t < 3; ++t) {
                int c = t * 16 + col;
                bb[t] = (c < NCLS) ? b2[c] : 0.f;
            }
            int nodeB = blockIdx.x * 16;
#pragma unroll
            for (int r = 0; r < 4; ++r) {
                int nd = nodeB + quad * 4 + r;
                float v0 = acc[0][r] + bb[0];
                float v1 = acc[1][r] + bb[1];
                float v2 = (col < 8) ? acc[2][r] + bb[2] : -INFINITY;
                float m = fmaxf(fmaxf(v0, v1), v2);
#pragma unroll
                for (int off = 1; off < 16; off <<= 1) m = fmaxf(m, __shfl_xor(m, off, 64));
                float s = expf(v0 - m) + expf(v1 - m) + ((col < 8) ? expf(v2 - m) : 0.f);
#pragma unroll
                for (int off = 1; off < 16; off <<= 1) s += __shfl_xor(s, off, 64);
                float ls = logf(s);
                if (nd < n) {
                    float* op = out + (size_t)nd * NCLS;
                    op[col]      = v0 - m - ls;
                    op[16 + col] = v1 - m - ls;
                    if (col < 8) op[32 + col] = v2 - m - ls;
                }
            }
        }
    }
}

extern "C" void kernel_launch(void* const* d_in, const int* in_sizes, int n_in,
                              void* d_out, int out_size, void* d_ws, size_t ws_size,
                              hipStream_t stream) {
    const float* x  = (const float*)d_in[0];
    const int*   ei = (const int*)d_in[1];
    const float* W1 = (const float*)d_in[2];
    const float* b1 = (const float*)d_in[3];
    const float* W2 = (const float*)d_in[4];
    const float* b2 = (const float*)d_in[5];
    float* out = (float*)d_out;

    int n = in_sizes[0] / F_IN;        // 100000
    int E = in_sizes[1] / 2;           // 3200000
    const int* src = ei;
    const int* dst = ei + E;
    int NB = (n + 127) >> 7;           // 782 dst buckets
    int nPart = (E + PART_CHUNK - 1) / PART_CHUNK;   // 782
    int nGemm1 = (n + 63) / 64;                      // 1563

    // workspace layout
    char* ws = (char*)d_ws;
    const size_t MB = 1024 * 1024;
    int*      bCur  = (int*)  (ws);                      // NB*8 ints (25 KB)
    int*      ptr   = (int*)  (ws + 128 * 1024);         // n ints (400 KB)
    int*      pEnd  = (int*)  (ws + 576 * 1024);         // n ints (400 KB)
    float*    dinv  = (float*)(ws + 1 * MB);             // n floats (400 KB)
    int*      sIdx  = (int*)     (ws + 2 * MB);          // NB*CAP ints SPARSE (14.4 MB)
    _Float16* bufA  = (_Float16*)(ws + 17 * MB);         // n*64 f16: h1 -> h1'  (12.8 MB)
    int*      pkBuf = (int*)     (ws + 30 * MB);         // NB*8*CAPX ints (19.2 MB)
    _Float16* bufB  = (_Float16*)(ws + 30 * MB);         // n*64 f16: h' — ALIASES pkBuf
                                                         // (pkBuf dead after bucket_finalize)

    hipMemsetAsync(bCur, 0, (size_t)NB * 8 * sizeof(int), stream);
    fused_part_gemm1<<<nPart + nGemm1, 256, 0, stream>>>(src, dst, bCur, pkBuf, E, NB, nPart,
                                                         x, W1, bufA, n);
    bucket_finalize<<<NB, 256, 0, stream>>>(bCur, pkBuf, ptr, pEnd, dinv, sIdx, bufA, n, E);

    // layer 1: h' = dinv*relu(dinv*A h1' + b1) -> bufB
    gather4<true ><<<(n + 15) / 16, 256, 0, stream>>>(ptr, pEnd, sIdx, dinv, bufA, b1, bufB,
                                                      W2, b2, out, n);
    // layer 2 FUSED: out = log_softmax((dinv*A h') @ W2 + b2)  (no g round-trip, no gemm2)
    gather4<false><<<(n + 15) / 16, 256, 0, stream>>>(ptr, pEnd, sIdx, dinv, bufB, b1, bufB,
                                                      W2, b2, out, n);
}

// Round 12
// 286.804 us; speedup vs baseline: 1.4096x; 1.4096x over previous
//
#include <hip/hip_runtime.h>
#include <math.h>

#define F_IN 128
#define HID  64
#define NCLS 40
#define PART_CHUNK 4096   // 782 partition blocks (parallelism)
#define CAP 4608          // total per-bucket capacity: mean 4096, sigma 64 -> 8 sigma headroom
#define CAPX 768          // per-(bucket,XCD) capacity: mean 512, sigma ~23 -> 11 sigma headroom
#define MAXNB 1024
#define ASTRIDE 132       // f16 row stride (128 + 4 pad)
#define GSTRIDE 72        // f16 row stride (64 + 8 pad) for fused gemm2 tiles

typedef _Float16 half8 __attribute__((ext_vector_type(8)));
typedef _Float16 half2t __attribute__((ext_vector_type(2)));
typedef float floatx4 __attribute__((ext_vector_type(4)));

// load 8 f16 from an 8B-aligned (not necessarily 16B) pointer (LDS staging use)
__device__ inline half8 ld_half8_u8(const _Float16* p) {
    union { uint2 u[2]; half8 h; } r;
    r.u[0] = *(const uint2*)p;
    r.u[1] = *(const uint2*)(p + 4);
    return r.h;
}

// ---------------- fused: edge partition | gemm1, INTERLEAVED (every 3rd block = partition) ----
// Roles interleave across blockIdx so latency-bound partition work and BW-bound gemm1 work
// co-reside on every CU for the whole kernel (blockIdx-ordered dispatch previously ran the
// two phases back-to-back, defeating the fusion).
// partition: LDS histogram + batched reservation (proven R9 body); pkBuf regions segregated
// by physical XCD (bid&7) so all writers of a 64B line share one private L2.
// gemm1: h1 = f16(x @ W1) via 16x16x32 f16 MFMA, 64 nodes/block.
__global__ __launch_bounds__(256) void fused_part_gemm1(const int* __restrict__ src,
                                                        const int* __restrict__ dst,
                                                        int* __restrict__ bCur,
                                                        int* __restrict__ pkBuf,
                                                        int E, int NB, int nPart,
                                                        const float* __restrict__ x,
                                                        const float* __restrict__ W1,
                                                        _Float16* __restrict__ h1, int n) {
    __shared__ __align__(16) char smem[2 * 64 * ASTRIDE * 2];   // 33792 B arena
    int tid = threadIdx.x;
    int bid = (int)blockIdx.x;
    int q = bid / 3;
    bool isPart = (bid % 3 == 0) && (q < nPart);
    if (isPart) {
        // ---- partition path (pid = q) ----
        int xcd = bid & 7;                 // physical-dispatch XCD heuristic; perf-only
        int* hcnt  = (int*)smem;           // [MAXNB]
        int* hbase = (int*)smem + MAXNB;   // [MAXNB]
        for (int i = tid; i < NB; i += 256) hcnt[i] = 0;
        __syncthreads();
        int e0 = q * PART_CHUNK;
        int s_[16], d_[16];
#pragma unroll
        for (int i = 0; i < 16; ++i) {
            int e = e0 + i * 256 + tid;
            if (e < E) {
                s_[i] = src[e]; d_[i] = dst[e];
                atomicAdd(&hcnt[d_[i] >> 7], 1);
            }
        }
        __syncthreads();
        for (int b = tid; b < NB; b += 256) {
            int c = hcnt[b];
            hbase[b] = c ? ((b * 8 + xcd) * CAPX + atomicAdd(&bCur[b * 8 + xcd], c)) : 0;
            hcnt[b] = 0;
        }
        __syncthreads();
#pragma unroll
        for (int i = 0; i < 16; ++i) {
            int e = e0 + i * 256 + tid;
            if (e < E) {
                int b = d_[i] >> 7;
                int loc = atomicAdd(&hcnt[b], 1);
                pkBuf[hbase[b] + loc] = (s_[i] << 7) | (d_[i] & 127);
            }
        }
    } else {
        // ---- gemm1 path ----
        int gid = (bid % 3 == 0) ? bid - nPart : bid - min(q + 1, nPart);
        _Float16* Ah = (_Float16*)smem;            // 64*ASTRIDE
        _Float16* Wt = Ah + 64 * ASTRIDE;          // 64*ASTRIDE
        int node0 = gid * 64;
#pragma unroll
        for (int i = 0; i < 8; ++i) {              // 8*256*4 = 8192 floats = 64x128
            int f = (i * 256 + tid) * 4;
            int m = f >> 7, k = f & 127;
            float4 v = (node0 + m < n) ? ((const float4*)(x + (size_t)(node0 + m) * F_IN))[k >> 2]
                                       : make_float4(0.f, 0.f, 0.f, 0.f);
            _Float16* p = &Ah[m * ASTRIDE + k];
            p[0] = (_Float16)v.x; p[1] = (_Float16)v.y; p[2] = (_Float16)v.z; p[3] = (_Float16)v.w;
        }
#pragma unroll
        for (int i = 0; i < 32; ++i) {
            int f = i * 256 + tid;                 // f = k*64 + nout
            int k = f >> 6, nn = f & 63;
            Wt[nn * ASTRIDE + k] = (_Float16)W1[f];
        }
        __syncthreads();
        int wave = tid >> 6, lane = tid & 63;
        int m0 = wave * 16;
        int col = lane & 15, quad = lane >> 4;
        floatx4 acc[4] = {{0,0,0,0},{0,0,0,0},{0,0,0,0},{0,0,0,0}};
#pragma unroll
        for (int kk = 0; kk < 4; ++kk) {
            int kbase = kk * 32 + quad * 8;
            half8 a = ld_half8_u8(&Ah[(m0 + col) * ASTRIDE + kbase]);
#pragma unroll
            for (int t = 0; t < 4; ++t) {
                half8 b = ld_half8_u8(&Wt[(t * 16 + col) * ASTRIDE + kbase]);
                acc[t] = __builtin_amdgcn_mfma_f32_16x16x32_f16(a, b, acc[t], 0, 0, 0);
            }
        }
#pragma unroll
        for (int t = 0; t < 4; ++t)
#pragma unroll
            for (int r = 0; r < 4; ++r) {
                int node = node0 + m0 + quad * 4 + r;
                if (node < n) h1[(size_t)node * HID + t * 16 + col] = (_Float16)acc[t][r];
            }
    }
}

// ---------------- per-bucket: gather 8 XCD segments -> LDS, counts -> ptr/pEnd + dinv,
//                  permute in LDS, stream sIdx to the bucket's FIXED sparse region (b*CAP),
//                  AND pre-scale h1 rows by dinv. No global scan needed (sparse layout).
__global__ __launch_bounds__(256) void bucket_finalize(const int* __restrict__ bCur,
                                                       const int* __restrict__ pkBuf,
                                                       int* __restrict__ ptr,
                                                       int* __restrict__ pEnd,
                                                       float* __restrict__ dinv,
                                                       int* __restrict__ sIdx,
                                                       _Float16* __restrict__ h1,
                                                       int n, int E) {
    __shared__ int cnt128[128];
    __shared__ int sc[128];
    __shared__ int cur[128];
    __shared__ float sdinv[128];
    __shared__ int segoff[9];
    __shared__ int ebuf[CAP];    // staged packed edges (18432 B)
    __shared__ int stage[CAP];   // permuted src indices (18432 B)
    int b = blockIdx.x;
    int node0 = b << 7;
    int tid = threadIdx.x;
    if (tid < 128) cnt128[tid] = 0;
    if (tid == 0) {
        int o = 0;
#pragma unroll
        for (int x = 0; x < 8; ++x) { segoff[x] = o; o += bCur[b * 8 + x]; }
        segoff[8] = o;
    }
    __syncthreads();
    int cnt = segoff[8];
    int dbase = b * CAP;               // fixed sparse region base (no scan)
    for (int x = 0; x < 8; ++x) {
        int off = segoff[x], len = segoff[x + 1] - off;
        const int* s = pkBuf + (size_t)(b * 8 + x) * CAPX;
        for (int j = tid; j < len; j += 256) {
            int p = s[j];
            ebuf[off + j] = p;
            atomicAdd(&cnt128[p & 127], 1);
        }
    }
    __syncthreads();
    // ---- 128-entry inclusive scan via 2-wave shfl ----
    int v = 0;
    if (tid < 128) {
        v = cnt128[tid];
        int vv = v;
        int lane = tid & 63;
#pragma unroll
        for (int off = 1; off < 64; off <<= 1) {
            int t = __shfl_up(vv, off, 64);
            if (lane >= off) vv += t;
        }
        sc[tid] = vv;
    }
    __syncthreads();
    if (tid >= 64 && tid < 128) sc[tid] += sc[63];
    __syncthreads();
    if (tid < 128) {
        cur[tid] = sc[tid] - v;            // LOCAL exclusive offset within bucket
        float dv = rsqrtf((float)v + 1.0f);   // +1 self loop
        sdinv[tid] = dv;
        int node = node0 + tid;
        if (node < n) {
            int p0 = dbase + sc[tid] - v;
            ptr[node] = p0;
            pEnd[node] = p0 + v;
            dinv[node] = dv;
        }
    }
    __syncthreads();
    for (int j = tid; j < cnt; j += 256) {
        int p = ebuf[j];
        int pos = atomicAdd(&cur[p & 127], 1);
        stage[pos] = p >> 7;
    }
    __syncthreads();
    for (int j = tid; j < cnt; j += 256)   // coalesced stream-out into the sparse region
        sIdx[dbase + j] = stage[j];
    // ---- in-place table pre-scale: h1[node] *= dinv[node] for this bucket's 128 nodes ----
#pragma unroll
    for (int pass = 0; pass < 4; ++pass) {
        int idx = pass * 256 + tid;
        int nd = node0 + (idx >> 3);
        if (nd < n) {
            float dv = sdinv[idx >> 3];
            half8* p = (half8*)(h1 + (size_t)nd * HID) + (idx & 7);
            half8 hv = *p;
#pragma unroll
            for (int j = 0; j < 8; ++j) hv[j] = (_Float16)((float)hv[j] * dv);
            *p = hv;
        }
    }
}

// ---------------- CSR gather: 4 nodes/wave, 16 lanes/node (2 slots x 8 chunks) ----
// 2-stage software pipeline (idx 2 iters ahead, rows 1 iter ahead).
// Table rows arrive PRE-SCALED by dinv[src]; loop is weight-free (validity masks only).
// RELU=true  (layer 1): stores h' = dinv[d] * relu(dinv[d]*sum + b1)  [pre-scaled for layer 2]
// RELU=false (layer 2, FUSED): g = dinv[d]*sum stays on-chip; block stages its 16 g-rows in
//   LDS and wave 0 computes out = log_softmax(g @ W2 + b2) directly.
template<bool RELU>
__global__ __launch_bounds__(256) void gather4(const int* __restrict__ ptr,
                                               const int* __restrict__ pEnd,
                                               const int* __restrict__ sIdx,
                                               const float* __restrict__ dinv,
                                               const _Float16* __restrict__ hin,
                                               const float* __restrict__ bias,
                                               _Float16* __restrict__ hout,
                                               const float* __restrict__ W2,
                                               const float* __restrict__ b2,
                                               float* __restrict__ out, int n) {
    __shared__ _Float16 gt[16 * GSTRIDE];   // 2304 B: 16 g-rows (fused path)
    __shared__ _Float16 wt[48 * GSTRIDE];   // 6912 B: W2^T zero-padded to 48 cols
    int tid = threadIdx.x, wave = tid >> 6, lane = tid & 63;
    int ng   = lane >> 4;         // node group 0..3
    int slot = (lane >> 3) & 1;   // edge slot 0..1
    int fq   = lane & 7;          // 16B chunk within 128B row
    int node = blockIdx.x * 16 + wave * 4 + ng;
    bool valid = node < n;
    int nodeC = valid ? node : 0;
    int beg = ptr[nodeC];
    int end = valid ? pEnd[nodeC] : beg;
    float di = dinv[nodeC];
    float a0[8] = {0,0,0,0,0,0,0,0}, a1[8] = {0,0,0,0,0,0,0,0};

    if (!RELU) {
        // stage W2^T (f32 -> f16) while the gather below hides the latency
#pragma unroll
        for (int i = 0; i < 12; ++i) {      // 3072 elems: f = c*64 + k
            int f = i * 256 + tid;
            int c = f >> 6, k = f & 63;
            wt[c * GSTRIDE + k] = (c < NCLS) ? (_Float16)W2[k * NCLS + c] : (_Float16)0.f;
        }
    }

    if (slot == 0 && valid) {     // self loop: table row already carries dinv[node]
        half8 v = *(const half8*)(hin + nodeC * HID + fq * 8);
#pragma unroll
        for (int j = 0; j < 8; ++j) a0[j] = (float)v[j];
    }
    const _Float16 ONE = (_Float16)1.0f, ZEROH = (_Float16)0.0f;
    if (beg < end) {
        // ---- pipeline preamble: idx(0), idx(1), rows(0) ----
        int ja0 = beg + slot, jb0 = ja0 + 2, jc0 = ja0 + 4, jd0 = ja0 + 6;
        bool va = ja0 < end, vb = jb0 < end, vc = jc0 < end, vd = jd0 < end;
        int sa0 = sIdx[va ? ja0 : beg];
        int sb0 = sIdx[vb ? jb0 : beg];
        int sc0 = sIdx[vc ? jc0 : beg];
        int sd0 = sIdx[vd ? jd0 : beg];
        int ja1 = ja0 + 8, jb1 = jb0 + 8, jc1 = jc0 + 8, jd1 = jd0 + 8;
        bool va1 = ja1 < end, vb1 = jb1 < end, vc1 = jc1 < end, vd1 = jd1 < end;
        int sa1 = sIdx[va1 ? ja1 : beg];
        int sb1 = sIdx[vb1 ? jb1 : beg];
        int sc1 = sIdx[vc1 ? jc1 : beg];
        int sd1 = sIdx[vd1 ? jd1 : beg];
        half8 ra = *(const half8*)(hin + (size_t)sa0 * HID + fq * 8);
        half8 rb = *(const half8*)(hin + (size_t)sb0 * HID + fq * 8);
        half8 rc = *(const half8*)(hin + (size_t)sc0 * HID + fq * 8);
        half8 rd = *(const half8*)(hin + (size_t)sd0 * HID + fq * 8);
        for (int j0 = beg; j0 < end; j0 += 8) {
            // issue rows(i+1) — indices already resolved last iteration
            half8 ra2 = *(const half8*)(hin + (size_t)sa1 * HID + fq * 8);
            half8 rb2 = *(const half8*)(hin + (size_t)sb1 * HID + fq * 8);
            half8 rc2 = *(const half8*)(hin + (size_t)sc1 * HID + fq * 8);
            half8 rd2 = *(const half8*)(hin + (size_t)sd1 * HID + fq * 8);
            // issue idx(i+2)
            int ja2 = j0 + 16 + slot, jb2 = ja2 + 2, jc2 = ja2 + 4, jd2 = ja2 + 6;
            bool va2 = ja2 < end, vb2 = jb2 < end, vc2 = jc2 < end, vd2 = jd2 < end;
            int sa2 = sIdx[va2 ? ja2 : beg];
            int sb2 = sIdx[vb2 ? jb2 : beg];
            int sc2 = sIdx[vc2 ? jc2 : beg];
            int sd2 = sIdx[vd2 ? jd2 : beg];
            // consume rows(i) — issued a full iteration ago
#if __has_builtin(__builtin_amdgcn_fdot2)
            half2t wab = { va ? ONE : ZEROH, vb ? ONE : ZEROH };
            half2t wcd = { vc ? ONE : ZEROH, vd ? ONE : ZEROH };
#pragma unroll
            for (int j = 0; j < 8; ++j) {
                half2t pab = { ra[j], rb[j] };
                half2t pcd = { rc[j], rd[j] };
                a0[j] = __builtin_amdgcn_fdot2(pab, wab, a0[j], false);
                a1[j] = __builtin_amdgcn_fdot2(pcd, wcd, a1[j], false);
            }
#else
            float wa = va ? 1.f : 0.f, wb = vb ? 1.f : 0.f, wc = vc ? 1.f : 0.f, wd = vd ? 1.f : 0.f;
#pragma unroll
            for (int j = 0; j < 8; ++j) {
                a0[j] = fmaf((float)ra[j], wa, a0[j]);
                a0[j] = fmaf((float)rb[j], wb, a0[j]);
                a1[j] = fmaf((float)rc[j], wc, a1[j]);
                a1[j] = fmaf((float)rd[j], wd, a1[j]);
            }
#endif
            // rotate pipeline state
            ra = ra2; rb = rb2; rc = rc2; rd = rd2;
            va = va1; vb = vb1; vc = vc1; vd = vd1;
            sa1 = sa2; sb1 = sb2; sc1 = sc2; sd1 = sd2;
            va1 = va2; vb1 = vb2; vc1 = vc2; vd1 = vd2;
        }
    }
#pragma unroll
    for (int j = 0; j < 8; ++j) {
        a0[j] += a1[j];
        a0[j] += __shfl_xor(a0[j], 8, 64);     // combine the 2 slots (1 round)
    }

    if (RELU) {
        // ---- layer-1 epilogue: store h' = dinv * relu(dinv*sum + b1) ----
        if (slot == 0 && valid) {
            union { half8 h; uint4 u; } o;
#pragma unroll
            for (int j = 0; j < 8; ++j) {
                float v = di * a0[j];
                v = fmaxf(v + bias[fq * 8 + j], 0.f) * di;   // pre-scale for next layer
                o.h[j] = (_Float16)v;
            }
            *(uint4*)(hout + nodeC * HID + fq * 8) = o.u;
        }
    } else {
        // ---- FUSED layer-2 epilogue: g-rows -> LDS, wave 0 does gemm2 + logsoftmax ----
        if (slot == 0) {
            int row = wave * 4 + ng;           // 0..15  (invalid nodes: a0 all zero)
#pragma unroll
            for (int j = 0; j < 8; ++j)
                gt[row * GSTRIDE + fq * 8 + j] = (_Float16)(di * a0[j]);
        }
        __syncthreads();
        if (wave == 0) {
            int col = lane & 15, quad = lane >> 4;
            floatx4 acc[3] = {{0,0,0,0},{0,0,0,0},{0,0,0,0}};
#pragma unroll
            for (int kk = 0; kk < 2; ++kk) {
                int kbase = kk * 32 + quad * 8;
                half8 a = *(const half8*)&gt[col * GSTRIDE + kbase];   // A[m=col][k]
#pragma unroll
                for (int t = 0; t < 3; ++t) {
                    half8 b = *(const half8*)&wt[(t * 16 + col) * GSTRIDE + kbase];
                    acc[t] = __builtin_amdgcn_mfma_f32_16x16x32_f16(a, b, acc[t], 0, 0, 0);
                }
            }
            float bb[3];
#pragma unroll
            for (int t = 0; t < 3; ++t) {
                int c = t * 16 + col;
                bb[t] = (c < NCLS) ? b2[c] : 0.f;
            }
            int nodeB = blockIdx.x * 16;
#pragma unroll
            for (int r = 0; r < 4; ++r) {
                int nd = nodeB + quad * 4 + r;
                float v0 = acc[0][r] + bb[0];
                float v1 = acc[1][r] + bb[1];
                float v2 = (col < 8) ? acc[2][r] + bb[2] : -INFINITY;
                float m = fmaxf(fmaxf(v0, v1), v2);
#pragma unroll
                for (int off = 1; off < 16; off <<= 1) m = fmaxf(m, __shfl_xor(m, off, 64));
                float s = expf(v0 - m) + expf(v1 - m) + ((col < 8) ? expf(v2 - m) : 0.f);
#pragma unroll
                for (int off = 1; off < 16; off <<= 1) s += __shfl_xor(s, off, 64);
                float ls = logf(s);
                if (nd < n) {
                    float* op = out + (size_t)nd * NCLS;
                    op[col]      = v0 - m - ls;
                    op[16 + col] = v1 - m - ls;
                    if (col < 8) op[32 + col] = v2 - m - ls;
                }
            }
        }
    }
}

extern "C" void kernel_launch(void* const* d_in, const int* in_sizes, int n_in,
                              void* d_out, int out_size, void* d_ws, size_t ws_size,
                              hipStream_t stream) {
    const float* x  = (const float*)d_in[0];
    const int*   ei = (const int*)d_in[1];
    const float* W1 = (const float*)d_in[2];
    const float* b1 = (const float*)d_in[3];
    const float* W2 = (const float*)d_in[4];
    const float* b2 = (const float*)d_in[5];
    float* out = (float*)d_out;

    int n = in_sizes[0] / F_IN;        // 100000
    int E = in_sizes[1] / 2;           // 3200000
    const int* src = ei;
    const int* dst = ei + E;
    int NB = (n + 127) >> 7;           // 782 dst buckets
    int nPart = (E + PART_CHUNK - 1) / PART_CHUNK;   // 782
    int nGemm1 = (n + 63) / 64;                      // 1563

    // workspace layout
    char* ws = (char*)d_ws;
    const size_t MB = 1024 * 1024;
    int*      bCur  = (int*)  (ws);                      // NB*8 ints (25 KB)
    int*      ptr   = (int*)  (ws + 128 * 1024);         // n ints (400 KB)
    int*      pEnd  = (int*)  (ws + 576 * 1024);         // n ints (400 KB)
    float*    dinv  = (float*)(ws + 1 * MB);             // n floats (400 KB)
    int*      sIdx  = (int*)     (ws + 2 * MB);          // NB*CAP ints SPARSE (14.4 MB)
    _Float16* bufA  = (_Float16*)(ws + 17 * MB);         // n*64 f16: h1 -> h1'  (12.8 MB)
    int*      pkBuf = (int*)     (ws + 30 * MB);         // NB*8*CAPX ints (19.2 MB)
    _Float16* bufB  = (_Float16*)(ws + 30 * MB);         // n*64 f16: h' — ALIASES pkBuf
                                                         // (pkBuf dead after bucket_finalize)

    hipMemsetAsync(bCur, 0, (size_t)NB * 8 * sizeof(int), stream);
    fused_part_gemm1<<<nPart + nGemm1, 256, 0, stream>>>(src, dst, bCur, pkBuf, E, NB, nPart,
                                                         x, W1, bufA, n);
    bucket_finalize<<<NB, 256, 0, stream>>>(bCur, pkBuf, ptr, pEnd, dinv, sIdx, bufA, n, E);

    // layer 1: h' = dinv*relu(dinv*A h1' + b1) -> bufB
    gather4<true ><<<(n + 15) / 16, 256, 0, stream>>>(ptr, pEnd, sIdx, dinv, bufA, b1, bufB,
                                                      W2, b2, out, n);
    // layer 2 FUSED: out = log_softmax((dinv*A h') @ W2 + b2)  (no g round-trip, no gemm2)
    gather4<false><<<(n + 15) / 16, 256, 0, stream>>>(ptr, pEnd, sIdx, dinv, bufB, b1, bufB,
                                                      W2, b2, out, n);
}

// Round 13
// 286.199 us; speedup vs baseline: 1.4126x; 1.0021x over previous
//
#include <hip/hip_runtime.h>
#include <math.h>

#define F_IN 128
#define HID  64
#define NCLS 40
#define PART_CHUNK 4096   // 782 partition blocks (parallelism)
#define CAP 4608          // total per-bucket capacity: mean 4096, sigma 64 -> 8 sigma headroom
#define CAPX 768          // per-(bucket,XCD) capacity: mean 512, sigma ~23 -> 11 sigma headroom
#define MAXNB 1024
#define ASTRIDE 132       // f16 row stride (128 + 4 pad)
#define GSTRIDE 72        // f16 row stride (64 + 8 pad) for fused gemm2 tiles

typedef _Float16 half8 __attribute__((ext_vector_type(8)));
typedef _Float16 half2t __attribute__((ext_vector_type(2)));
typedef float floatx4 __attribute__((ext_vector_type(4)));

// load 8 f16 from an 8B-aligned (not necessarily 16B) pointer (LDS staging use)
__device__ inline half8 ld_half8_u8(const _Float16* p) {
    union { uint2 u[2]; half8 h; } r;
    r.u[0] = *(const uint2*)p;
    r.u[1] = *(const uint2*)(p + 4);
    return r.h;
}

// ---------------- fused: edge partition | gemm1, INTERLEAVED (every 3rd block = partition) ----
// Roles interleave across blockIdx so latency-bound partition work and BW-bound gemm1 work
// co-reside on every CU for the whole kernel.
// partition: LDS histogram + batched reservation; pkBuf regions segregated by physical XCD
// (bid&7) so all writers of a 64B line share one private L2 (partial writes merge).
// gemm1: h1 = f16(x @ W1) via 16x16x32 f16 MFMA, 64 nodes/block.
__global__ __launch_bounds__(256) void fused_part_gemm1(const int* __restrict__ src,
                                                        const int* __restrict__ dst,
                                                        int* __restrict__ bCur,
                                                        int* __restrict__ pkBuf,
                                                        int E, int NB, int nPart,
                                                        const float* __restrict__ x,
                                                        const float* __restrict__ W1,
                                                        _Float16* __restrict__ h1, int n) {
    __shared__ __align__(16) char smem[2 * 64 * ASTRIDE * 2];   // 33792 B arena
    int tid = threadIdx.x;
    int bid = (int)blockIdx.x;
    int q = bid / 3;
    bool isPart = (bid % 3 == 0) && (q < nPart);
    if (isPart) {
        // ---- partition path (pid = q) ----
        int xcd = bid & 7;                 // physical-dispatch XCD heuristic; perf-only
        int* hcnt  = (int*)smem;           // [MAXNB]
        int* hbase = (int*)smem + MAXNB;   // [MAXNB]
        for (int i = tid; i < NB; i += 256) hcnt[i] = 0;
        __syncthreads();
        int e0 = q * PART_CHUNK;
        int s_[16], d_[16];
#pragma unroll
        for (int i = 0; i < 16; ++i) {
            int e = e0 + i * 256 + tid;
            if (e < E) {
                s_[i] = src[e]; d_[i] = dst[e];
                atomicAdd(&hcnt[d_[i] >> 7], 1);
            }
        }
        __syncthreads();
        for (int b = tid; b < NB; b += 256) {
            int c = hcnt[b];
            hbase[b] = c ? ((b * 8 + xcd) * CAPX + atomicAdd(&bCur[b * 8 + xcd], c)) : 0;
            hcnt[b] = 0;
        }
        __syncthreads();
#pragma unroll
        for (int i = 0; i < 16; ++i) {
            int e = e0 + i * 256 + tid;
            if (e < E) {
                int b = d_[i] >> 7;
                int loc = atomicAdd(&hcnt[b], 1);
                pkBuf[hbase[b] + loc] = (s_[i] << 7) | (d_[i] & 127);
            }
        }
    } else {
        // ---- gemm1 path ----
        int gid = (bid % 3 == 0) ? bid - nPart : bid - min(q + 1, nPart);
        _Float16* Ah = (_Float16*)smem;            // 64*ASTRIDE
        _Float16* Wt = Ah + 64 * ASTRIDE;          // 64*ASTRIDE
        int node0 = gid * 64;
#pragma unroll
        for (int i = 0; i < 8; ++i) {              // 8*256*4 = 8192 floats = 64x128
            int f = (i * 256 + tid) * 4;
            int m = f >> 7, k = f & 127;
            float4 v = (node0 + m < n) ? ((const float4*)(x + (size_t)(node0 + m) * F_IN))[k >> 2]
                                       : make_float4(0.f, 0.f, 0.f, 0.f);
            _Float16* p = &Ah[m * ASTRIDE + k];
            p[0] = (_Float16)v.x; p[1] = (_Float16)v.y; p[2] = (_Float16)v.z; p[3] = (_Float16)v.w;
        }
#pragma unroll
        for (int i = 0; i < 32; ++i) {
            int f = i * 256 + tid;                 // f = k*64 + nout
            int k = f >> 6, nn = f & 63;
            Wt[nn * ASTRIDE + k] = (_Float16)W1[f];
        }
        __syncthreads();
        int wave = tid >> 6, lane = tid & 63;
        int m0 = wave * 16;
        int col = lane & 15, quad = lane >> 4;
        floatx4 acc[4] = {{0,0,0,0},{0,0,0,0},{0,0,0,0},{0,0,0,0}};
#pragma unroll
        for (int kk = 0; kk < 4; ++kk) {
            int kbase = kk * 32 + quad * 8;
            half8 a = ld_half8_u8(&Ah[(m0 + col) * ASTRIDE + kbase]);
#pragma unroll
            for (int t = 0; t < 4; ++t) {
                half8 b = ld_half8_u8(&Wt[(t * 16 + col) * ASTRIDE + kbase]);
                acc[t] = __builtin_amdgcn_mfma_f32_16x16x32_f16(a, b, acc[t], 0, 0, 0);
            }
        }
#pragma unroll
        for (int t = 0; t < 4; ++t)
#pragma unroll
            for (int r = 0; r < 4; ++r) {
                int node = node0 + m0 + quad * 4 + r;
                if (node < n) h1[(size_t)node * HID + t * 16 + col] = (_Float16)acc[t][r];
            }
    }
}

// ---------------- per-bucket: count pass over 8 XCD segments, counts -> ptr/pEnd + dinv,
//                  permute pass RE-READS pkBuf (L2-hot) -> stage in LDS, stream sIdx out.
//                  No ebuf staging: LDS 38.9KB -> ~20.5KB, blocks/CU 4 -> 7 (latency-bound
//                  kernel, 2x TLP). Also pre-scales h1 rows by dinv.
__global__ __launch_bounds__(256) void bucket_finalize(const int* __restrict__ bCur,
                                                       const int* __restrict__ pkBuf,
                                                       int* __restrict__ ptr,
                                                       int* __restrict__ pEnd,
                                                       float* __restrict__ dinv,
                                                       int* __restrict__ sIdx,
                                                       _Float16* __restrict__ h1,
                                                       int n, int E) {
    __shared__ int cnt128[128];
    __shared__ int sc[128];
    __shared__ int cur[128];
    __shared__ float sdinv[128];
    __shared__ int segoff[9];
    __shared__ int stage[CAP];   // permuted src indices (18432 B)
    int b = blockIdx.x;
    int node0 = b << 7;
    int tid = threadIdx.x;
    if (tid < 128) cnt128[tid] = 0;
    if (tid == 0) {
        int o = 0;
#pragma unroll
        for (int x = 0; x < 8; ++x) { segoff[x] = o; o += bCur[b * 8 + x]; }
        segoff[8] = o;
    }
    __syncthreads();
    int cnt = segoff[8];
    int dbase = b * CAP;               // fixed sparse region base (no scan)
    // ---- pass A: count (streaming read of this bucket's 8 segments) ----
    for (int x = 0; x < 8; ++x) {
        int off = segoff[x], len = segoff[x + 1] - off;
        const int* s = pkBuf + (size_t)(b * 8 + x) * CAPX;
        for (int j = tid; j < len; j += 256)
            atomicAdd(&cnt128[s[j] & 127], 1);
    }
    __syncthreads();
    // ---- 128-entry inclusive scan via 2-wave shfl ----
    int v = 0;
    if (tid < 128) {
        v = cnt128[tid];
        int vv = v;
        int lane = tid & 63;
#pragma unroll
        for (int off = 1; off < 64; off <<= 1) {
            int t = __shfl_up(vv, off, 64);
            if (lane >= off) vv += t;
        }
        sc[tid] = vv;
    }
    __syncthreads();
    if (tid >= 64 && tid < 128) sc[tid] += sc[63];
    __syncthreads();
    if (tid < 128) {
        cur[tid] = sc[tid] - v;            // LOCAL exclusive offset within bucket
        float dv = rsqrtf((float)v + 1.0f);   // +1 self loop
        sdinv[tid] = dv;
        int node = node0 + tid;
        if (node < n) {
            int p0 = dbase + sc[tid] - v;
            ptr[node] = p0;
            pEnd[node] = p0 + v;
            dinv[node] = dv;
        }
    }
    __syncthreads();
    // ---- pass B: permute (re-read pkBuf — L2/LLC-hot from pass A) ----
    for (int x = 0; x < 8; ++x) {
        int off = segoff[x], len = segoff[x + 1] - off;
        const int* s = pkBuf + (size_t)(b * 8 + x) * CAPX;
        for (int j = tid; j < len; j += 256) {
            int p = s[j];
            int pos = atomicAdd(&cur[p & 127], 1);
            stage[pos] = p >> 7;
        }
    }
    __syncthreads();
    for (int j = tid; j < cnt; j += 256)   // coalesced stream-out into the sparse region
        sIdx[dbase + j] = stage[j];
    // ---- in-place table pre-scale: h1[node] *= dinv[node] for this bucket's 128 nodes ----
#pragma unroll
    for (int pass = 0; pass < 4; ++pass) {
        int idx = pass * 256 + tid;
        int nd = node0 + (idx >> 3);
        if (nd < n) {
            float dv = sdinv[idx >> 3];
            half8* p = (half8*)(h1 + (size_t)nd * HID) + (idx & 7);
            half8 hv = *p;
#pragma unroll
            for (int j = 0; j < 8; ++j) hv[j] = (_Float16)((float)hv[j] * dv);
            *p = hv;
        }
    }
}

// ---------------- CSR gather: 4 nodes/wave, 16 lanes/node (2 slots x 8 chunks) ----
// 2-stage software pipeline (idx 2 iters ahead, rows 1 iter ahead).
// Table rows arrive PRE-SCALED by dinv[src]; loop is weight-free (validity masks only).
// RELU=true  (layer 1): stores h' = dinv[d] * relu(dinv[d]*sum + b1)  [pre-scaled for layer 2]
// RELU=false (layer 2, FUSED): g = dinv[d]*sum stays on-chip; block stages its 16 g-rows in
//   LDS and wave 0 computes out = log_softmax(g @ W2 + b2) directly.
template<bool RELU>
__global__ __launch_bounds__(256) void gather4(const int* __restrict__ ptr,
                                               const int* __restrict__ pEnd,
                                               const int* __restrict__ sIdx,
                                               const float* __restrict__ dinv,
                                               const _Float16* __restrict__ hin,
                                               const float* __restrict__ bias,
                                               _Float16* __restrict__ hout,
                                               const float* __restrict__ W2,
                                               const float* __restrict__ b2,
                                               float* __restrict__ out, int n) {
    __shared__ _Float16 gt[16 * GSTRIDE];   // 2304 B: 16 g-rows (fused path)
    __shared__ _Float16 wt[48 * GSTRIDE];   // 6912 B: W2^T zero-padded to 48 cols
    int tid = threadIdx.x, wave = tid >> 6, lane = tid & 63;
    int ng   = lane >> 4;         // node group 0..3
    int slot = (lane >> 3) & 1;   // edge slot 0..1
    int fq   = lane & 7;          // 16B chunk within 128B row
    int node = blockIdx.x * 16 + wave * 4 + ng;
    bool valid = node < n;
    int nodeC = valid ? node : 0;
    int beg = ptr[nodeC];
    int end = valid ? pEnd[nodeC] : beg;
    float di = dinv[nodeC];
    float a0[8] = {0,0,0,0,0,0,0,0}, a1[8] = {0,0,0,0,0,0,0,0};

    if (!RELU) {
        // stage W2^T (f32 -> f16) while the gather below hides the latency
#pragma unroll
        for (int i = 0; i < 12; ++i) {      // 3072 elems: f = c*64 + k
            int f = i * 256 + tid;
            int c = f >> 6, k = f & 63;
            wt[c * GSTRIDE + k] = (c < NCLS) ? (_Float16)W2[k * NCLS + c] : (_Float16)0.f;
        }
    }

    if (slot == 0 && valid) {     // self loop: table row already carries dinv[node]
        half8 v = *(const half8*)(hin + nodeC * HID + fq * 8);
#pragma unroll
        for (int j = 0; j < 8; ++j) a0[j] = (float)v[j];
    }
    const _Float16 ONE = (_Float16)1.0f, ZEROH = (_Float16)0.0f;
    if (beg < end) {
        // ---- pipeline preamble: idx(0), idx(1), rows(0) ----
        int ja0 = beg + slot, jb0 = ja0 + 2, jc0 = ja0 + 4, jd0 = ja0 + 6;
        bool va = ja0 < end, vb = jb0 < end, vc = jc0 < end, vd = jd0 < end;
        int sa0 = sIdx[va ? ja0 : beg];
        int sb0 = sIdx[vb ? jb0 : beg];
        int sc0 = sIdx[vc ? jc0 : beg];
        int sd0 = sIdx[vd ? jd0 : beg];
        int ja1 = ja0 + 8, jb1 = jb0 + 8, jc1 = jc0 + 8, jd1 = jd0 + 8;
        bool va1 = ja1 < end, vb1 = jb1 < end, vc1 = jc1 < end, vd1 = jd1 < end;
        int sa1 = sIdx[va1 ? ja1 : beg];
        int sb1 = sIdx[vb1 ? jb1 : beg];
        int sc1 = sIdx[vc1 ? jc1 : beg];
        int sd1 = sIdx[vd1 ? jd1 : beg];
        half8 ra = *(const half8*)(hin + (size_t)sa0 * HID + fq * 8);
        half8 rb = *(const half8*)(hin + (size_t)sb0 * HID + fq * 8);
        half8 rc = *(const half8*)(hin + (size_t)sc0 * HID + fq * 8);
        half8 rd = *(const half8*)(hin + (size_t)sd0 * HID + fq * 8);
        for (int j0 = beg; j0 < end; j0 += 8) {
            // issue rows(i+1) — indices already resolved last iteration
            half8 ra2 = *(const half8*)(hin + (size_t)sa1 * HID + fq * 8);
            half8 rb2 = *(const half8*)(hin + (size_t)sb1 * HID + fq * 8);
            half8 rc2 = *(const half8*)(hin + (size_t)sc1 * HID + fq * 8);
            half8 rd2 = *(const half8*)(hin + (size_t)sd1 * HID + fq * 8);
            // issue idx(i+2)
            int ja2 = j0 + 16 + slot, jb2 = ja2 + 2, jc2 = ja2 + 4, jd2 = ja2 + 6;
            bool va2 = ja2 < end, vb2 = jb2 < end, vc2 = jc2 < end, vd2 = jd2 < end;
            int sa2 = sIdx[va2 ? ja2 : beg];
            int sb2 = sIdx[vb2 ? jb2 : beg];
            int sc2 = sIdx[vc2 ? jc2 : beg];
            int sd2 = sIdx[vd2 ? jd2 : beg];
            // consume rows(i) — issued a full iteration ago
#if __has_builtin(__builtin_amdgcn_fdot2)
            half2t wab = { va ? ONE : ZEROH, vb ? ONE : ZEROH };
            half2t wcd = { vc ? ONE : ZEROH, vd ? ONE : ZEROH };
#pragma unroll
            for (int j = 0; j < 8; ++j) {
                half2t pab = { ra[j], rb[j] };
                half2t pcd = { rc[j], rd[j] };
                a0[j] = __builtin_amdgcn_fdot2(pab, wab, a0[j], false);
                a1[j] = __builtin_amdgcn_fdot2(pcd, wcd, a1[j], false);
            }
#else
            float wa = va ? 1.f : 0.f, wb = vb ? 1.f : 0.f, wc = vc ? 1.f : 0.f, wd = vd ? 1.f : 0.f;
#pragma unroll
            for (int j = 0; j < 8; ++j) {
                a0[j] = fmaf((float)ra[j], wa, a0[j]);
                a0[j] = fmaf((float)rb[j], wb, a0[j]);
                a1[j] = fmaf((float)rc[j], wc, a1[j]);
                a1[j] = fmaf((float)rd[j], wd, a1[j]);
            }
#endif
            // rotate pipeline state
            ra = ra2; rb = rb2; rc = rc2; rd = rd2;
            va = va1; vb = vb1; vc = vc1; vd = vd1;
            sa1 = sa2; sb1 = sb2; sc1 = sc2; sd1 = sd2;
            va1 = va2; vb1 = vb2; vc1 = vc2; vd1 = vd2;
        }
    }
#pragma unroll
    for (int j = 0; j < 8; ++j) {
        a0[j] += a1[j];
        a0[j] += __shfl_xor(a0[j], 8, 64);     // combine the 2 slots (1 round)
    }

    if (RELU) {
        // ---- layer-1 epilogue: store h' = dinv * relu(dinv*sum + b1) ----
        if (slot == 0 && valid) {
            union { half8 h; uint4 u; } o;
#pragma unroll
            for (int j = 0; j < 8; ++j) {
                float v = di * a0[j];
                v = fmaxf(v + bias[fq * 8 + j], 0.f) * di;   // pre-scale for next layer
                o.h[j] = (_Float16)v;
            }
            *(uint4*)(hout + nodeC * HID + fq * 8) = o.u;
        }
    } else {
        // ---- FUSED layer-2 epilogue: g-rows -> LDS, wave 0 does gemm2 + logsoftmax ----
        if (slot == 0) {
            int row = wave * 4 + ng;           // 0..15  (invalid nodes: a0 all zero)
#pragma unroll
            for (int j = 0; j < 8; ++j)
                gt[row * GSTRIDE + fq * 8 + j] = (_Float16)(di * a0[j]);
        }
        __syncthreads();
        if (wave == 0) {
            int col = lane & 15, quad = lane >> 4;
            floatx4 acc[3] = {{0,0,0,0},{0,0,0,0},{0,0,0,0}};
#pragma unroll
            for (int kk = 0; kk < 2; ++kk) {
                int kbase = kk * 32 + quad * 8;
                half8 a = *(const half8*)&gt[col * GSTRIDE + kbase];   // A[m=col][k]
#pragma unroll
                for (int t = 0; t < 3; ++t) {
                    half8 b = *(const half8*)&wt[(t * 16 + col) * GSTRIDE + kbase];
                    acc[t] = __builtin_amdgcn_mfma_f32_16x16x32_f16(a, b, acc[t], 0, 0, 0);
                }
            }
            float bb[3];
#pragma unroll
            for (int t = 0; t < 3; ++t) {
                int c = t * 16 + col;
                bb[t] = (c < NCLS) ? b2[c] : 0.f;
            }
            int nodeB = blockIdx.x * 16;
#pragma unroll
            for (int r = 0; r < 4; ++r) {
                int nd = nodeB + quad * 4 + r;
                float v0 = acc[0][r] + bb[0];
                float v1 = acc[1][r] + bb[1];
                float v2 = (col < 8) ? acc[2][r] + bb[2] : -INFINITY;
                float m = fmaxf(fmaxf(v0, v1), v2);
#pragma unroll
                for (int off = 1; off < 16; off <<= 1) m = fmaxf(m, __shfl_xor(m, off, 64));
                float s = expf(v0 - m) + expf(v1 - m) + ((col < 8) ? expf(v2 - m) : 0.f);
#pragma unroll
                for (int off = 1; off < 16; off <<= 1) s += __shfl_xor(s, off, 64);
                float ls = logf(s);
                if (nd < n) {
                    float* op = out + (size_t)nd * NCLS;
                    op[col]      = v0 - m - ls;
                    op[16 + col] = v1 - m - ls;
                    if (col < 8) op[32 + col] = v2 - m - ls;
                }
            }
        }
    }
}

extern "C" void kernel_launch(void* const* d_in, const int* in_sizes, int n_in,
                              void* d_out, int out_size, void* d_ws, size_t ws_size,
                              hipStream_t stream) {
    const float* x  = (const float*)d_in[0];
    const int*   ei = (const int*)d_in[1];
    const float* W1 = (const float*)d_in[2];
    const float* b1 = (const float*)d_in[3];
    const float* W2 = (const float*)d_in[4];
    const float* b2 = (const float*)d_in[5];
    float* out = (float*)d_out;

    int n = in_sizes[0] / F_IN;        // 100000
    int E = in_sizes[1] / 2;           // 3200000
    const int* src = ei;
    const int* dst = ei + E;
    int NB = (n + 127) >> 7;           // 782 dst buckets
    int nPart = (E + PART_CHUNK - 1) / PART_CHUNK;   // 782
    int nGemm1 = (n + 63) / 64;                      // 1563

    // workspace layout
    char* ws = (char*)d_ws;
    const size_t MB = 1024 * 1024;
    int*      bCur  = (int*)  (ws);                      // NB*8 ints (25 KB)
    int*      ptr   = (int*)  (ws + 128 * 1024);         // n ints (400 KB)
    int*      pEnd  = (int*)  (ws + 576 * 1024);         // n ints (400 KB)
    float*    dinv  = (float*)(ws + 1 * MB);             // n floats (400 KB)
    int*      sIdx  = (int*)     (ws + 2 * MB);          // NB*CAP ints SPARSE (14.4 MB)
    _Float16* bufA  = (_Float16*)(ws + 17 * MB);         // n*64 f16: h1 -> h1'  (12.8 MB)
    int*      pkBuf = (int*)     (ws + 30 * MB);         // NB*8*CAPX ints (19.2 MB)
    _Float16* bufB  = (_Float16*)(ws + 30 * MB);         // n*64 f16: h' — ALIASES pkBuf
                                                         // (pkBuf dead after bucket_finalize)

    hipMemsetAsync(bCur, 0, (size_t)NB * 8 * sizeof(int), stream);
    fused_part_gemm1<<<nPart + nGemm1, 256, 0, stream>>>(src, dst, bCur, pkBuf, E, NB, nPart,
                                                         x, W1, bufA, n);
    bucket_finalize<<<NB, 256, 0, stream>>>(bCur, pkBuf, ptr, pEnd, dinv, sIdx, bufA, n, E);

    // layer 1: h' = dinv*relu(dinv*A h1' + b1) -> bufB
    gather4<true ><<<(n + 15) / 16, 256, 0, stream>>>(ptr, pEnd, sIdx, dinv, bufA, b1, bufB,
                                                      W2, b2, out, n);
    // layer 2 FUSED: out = log_softmax((dinv*A h') @ W2 + b2)  (no g round-trip, no gemm2)
    gather4<false><<<(n + 15) / 16, 256, 0, stream>>>(ptr, pEnd, sIdx, dinv, bufB, b1, bufB,
                                                      W2, b2, out, n);
}